// Round 1
// baseline (84.693 us; speedup 1.0000x reference)
//
#include <hip/hip_runtime.h>

#define BATCH 8192
#define DIM 128
#define MARGIN 1.0f

// One wave (64 lanes) per batch element; 4 waves per block.
// Each lane owns 2 columns (float2). Column-accumulator formulation:
//   colacc_p[j] = sum_i dp[i]*W[i][j];  pos = sum_j colacc_p[j]*dp[j]
// so only ONE cross-lane reduction per element, and W is read once for
// both pos and neg quadratic forms.
__global__ __launch_bounds__(256) void transa_score_kernel(
    const float* __restrict__ pos_b, const float* __restrict__ neg_b,
    const int* __restrict__ r_idx, const float* __restrict__ rel_emb,
    float* __restrict__ partial) {
  __shared__ float s_dp[4][DIM];
  __shared__ float s_dn[4][DIM];
  const int wave = threadIdx.x >> 6;
  const int lane = threadIdx.x & 63;
  const int idx = blockIdx.x * 4 + wave;
  const int c0 = lane * 2;

  const float* pb = pos_b + (size_t)idx * (3 * DIM);
  const float* nb = neg_b + (size_t)idx * (3 * DIM);
  float2 hp = *(const float2*)(pb + c0);
  float2 rp = *(const float2*)(pb + DIM + c0);
  float2 tp = *(const float2*)(pb + 2 * DIM + c0);
  float2 hn = *(const float2*)(nb + c0);
  float2 rn = *(const float2*)(nb + DIM + c0);
  float2 tn = *(const float2*)(nb + 2 * DIM + c0);

  float2 dp2, dn2;
  dp2.x = fabsf(hp.x + rp.x - tp.x);
  dp2.y = fabsf(hp.y + rp.y - tp.y);
  dn2.x = fabsf(hn.x + rn.x - tn.x);
  dn2.y = fabsf(hn.y + rn.y - tn.y);

  s_dp[wave][c0] = dp2.x;
  s_dp[wave][c0 + 1] = dp2.y;
  s_dn[wave][c0] = dn2.x;
  s_dn[wave][c0 + 1] = dn2.y;
  __syncthreads();

  const float* W = rel_emb + (size_t)r_idx[idx] * (DIM * DIM) + c0;

  float2 accp = make_float2(0.f, 0.f);
  float2 accn = make_float2(0.f, 0.f);
#pragma unroll 8
  for (int i = 0; i < DIM; ++i) {
    float2 w = *(const float2*)(W + (size_t)i * DIM);
    float dip = s_dp[wave][i];  // broadcast read, conflict-free
    float din = s_dn[wave][i];
    accp.x = fmaf(dip, w.x, accp.x);
    accp.y = fmaf(dip, w.y, accp.y);
    accn.x = fmaf(din, w.x, accn.x);
    accn.y = fmaf(din, w.y, accn.y);
  }

  // per-lane partial of (pos - neg)
  float s = accp.x * dp2.x + accp.y * dp2.y - accn.x * dn2.x - accn.y * dn2.y;
#pragma unroll
  for (int o = 32; o > 0; o >>= 1) s += __shfl_xor(s, o, 64);

  if (lane == 0) partial[idx] = s;
}

// Single-block deterministic reduction: mean(relu(MARGIN + (pos - neg)))
__global__ __launch_bounds__(256) void transa_reduce_kernel(
    const float* __restrict__ partial, float* __restrict__ out) {
  float acc = 0.f;
  for (int i = threadIdx.x; i < BATCH; i += 256) {
    float v = MARGIN + partial[i];
    acc += (v > 0.f) ? v : 0.f;
  }
#pragma unroll
  for (int o = 32; o > 0; o >>= 1) acc += __shfl_xor(acc, o, 64);

  __shared__ float s[4];
  const int lane = threadIdx.x & 63;
  const int wave = threadIdx.x >> 6;
  if (lane == 0) s[wave] = acc;
  __syncthreads();
  if (threadIdx.x == 0) {
    out[0] = (s[0] + s[1] + s[2] + s[3]) * (1.0f / BATCH);
  }
}

extern "C" void kernel_launch(void* const* d_in, const int* in_sizes, int n_in,
                              void* d_out, int out_size, void* d_ws, size_t ws_size,
                              hipStream_t stream) {
  const float* pos_b = (const float*)d_in[0];
  const float* neg_b = (const float*)d_in[1];
  const int* r_idx = (const int*)d_in[2];
  const float* rel_emb = (const float*)d_in[3];
  float* out = (float*)d_out;
  float* partial = (float*)d_ws;  // BATCH floats

  transa_score_kernel<<<BATCH / 4, 256, 0, stream>>>(pos_b, neg_b, r_idx,
                                                     rel_emb, partial);
  transa_reduce_kernel<<<1, 256, 0, stream>>>(partial, out);
}

// Round 2
// 68.072 us; speedup vs baseline: 1.2442x; 1.2442x over previous
//
#include <hip/hip_runtime.h>

#define BATCH 8192
#define DIM 128
#define NREL 1000
#define MARGIN 1.0f

// Workspace layout (int/float units, 4 B each):
//   [0      .. 8191 ]  partial   (float, per-element pos-neg score)
//   [8192   .. 9215 ]  cnt       (int, NREL padded to 1024)
//   [9216   .. 10239]  start     (int)
//   [10240  .. 11263]  cursor    (int)
//   [11264  .. 19455]  order     (int, BATCH)
#define WS_PARTIAL 0
#define WS_CNT     8192
#define WS_START   9216
#define WS_CURSOR  10240
#define WS_ORDER   11264

__global__ __launch_bounds__(256) void zero_kernel(int* cnt) {
  for (int i = threadIdx.x; i < 1024; i += 256) cnt[i] = 0;
}

__global__ __launch_bounds__(256) void count_kernel(const int* __restrict__ r_idx,
                                                    int* __restrict__ cnt) {
  int i = blockIdx.x * 256 + threadIdx.x;
  if (i < BATCH) atomicAdd(&cnt[r_idx[i]], 1);
}

// Single-block exclusive scan over NREL counters (padded to 1024).
__global__ __launch_bounds__(256) void scan_kernel(const int* __restrict__ cnt,
                                                   int* __restrict__ start,
                                                   int* __restrict__ cursor) {
  int tid = threadIdx.x, lane = tid & 63, wave = tid >> 6;
  int base = tid * 4;
  int c[4], lsum = 0;
#pragma unroll
  for (int k = 0; k < 4; ++k) {
    int i = base + k;
    c[k] = (i < NREL) ? cnt[i] : 0;
    lsum += c[k];
  }
  int v = lsum;  // inclusive scan of thread sums within wave
#pragma unroll
  for (int o = 1; o < 64; o <<= 1) {
    int u = __shfl_up(v, o, 64);
    if (lane >= o) v += u;
  }
  __shared__ int wsum[4];
  if (lane == 63) wsum[wave] = v;
  __syncthreads();
  int woff = 0;
  for (int w = 0; w < wave; ++w) woff += wsum[w];
  int toff = woff + v - lsum;  // exclusive offset for this thread's 4 counters
#pragma unroll
  for (int k = 0; k < 4; ++k) {
    int i = base + k;
    if (i < NREL) {
      start[i] = toff;
      cursor[i] = toff;
    }
    toff += c[k];
  }
}

__global__ __launch_bounds__(256) void scatter_kernel(const int* __restrict__ r_idx,
                                                      int* __restrict__ cursor,
                                                      int* __restrict__ order) {
  int i = blockIdx.x * 256 + threadIdx.x;
  if (i < BATCH) {
    int p = atomicAdd(&cursor[r_idx[i]], 1);
    order[p] = i;
  }
}

__device__ inline float2 dvec(const float* __restrict__ b, int c0) {
  float2 h = *(const float2*)(b + c0);
  float2 r = *(const float2*)(b + DIM + c0);
  float2 t = *(const float2*)(b + 2 * DIM + c0);
  return make_float2(fabsf(h.x + r.x - t.x), fabsf(h.y + r.y - t.y));
}

// One block per relation. Stage W (64 KB) in dynamic LDS once; 4 waves
// each process 2 batch elements per pass against the staged W.
__global__ __launch_bounds__(256) void score_kernel(
    const float* __restrict__ pos_b, const float* __restrict__ neg_b,
    const float* __restrict__ rel_emb, const int* __restrict__ cnt,
    const int* __restrict__ start, const int* __restrict__ order,
    float* __restrict__ partial) {
  extern __shared__ float sW[];          // DIM*DIM floats = 64 KB
  __shared__ float s_d[4][DIM][4];       // [wave][row][{p0,n0,p1,n1}] = 8 KB
  const int r = blockIdx.x;
  const int n = cnt[r];
  if (n == 0) return;
  const int base = start[r];
  const int tid = threadIdx.x, lane = tid & 63, wave = tid >> 6;
  const int c0 = lane * 2;

  const float* Wg = rel_emb + (size_t)r * (DIM * DIM);
  for (int k = tid; k < DIM * DIM / 4; k += 256)
    *(float4*)(sW + k * 4) = *(const float4*)(Wg + k * 4);
  __syncthreads();

  const int passes = (n + 7) >> 3;  // 8 elements per pass (2 per wave)
  for (int p = 0; p < passes; ++p) {
    const int k0 = p * 8 + wave * 2;
    const bool v0 = k0 < n, v1 = (k0 + 1) < n;
    const int e0 = v0 ? order[base + k0] : 0;
    const int e1 = v1 ? order[base + k0 + 1] : 0;

    const float2 z = make_float2(0.f, 0.f);
    float2 dp0 = v0 ? dvec(pos_b + (size_t)e0 * 3 * DIM, c0) : z;
    float2 dn0 = v0 ? dvec(neg_b + (size_t)e0 * 3 * DIM, c0) : z;
    float2 dp1 = v1 ? dvec(pos_b + (size_t)e1 * 3 * DIM, c0) : z;
    float2 dn1 = v1 ? dvec(neg_b + (size_t)e1 * 3 * DIM, c0) : z;

    s_d[wave][c0][0] = dp0.x;  s_d[wave][c0 + 1][0] = dp0.y;
    s_d[wave][c0][1] = dn0.x;  s_d[wave][c0 + 1][1] = dn0.y;
    s_d[wave][c0][2] = dp1.x;  s_d[wave][c0 + 1][2] = dp1.y;
    s_d[wave][c0][3] = dn1.x;  s_d[wave][c0 + 1][3] = dn1.y;
    __syncthreads();  // uniform: passes identical across waves

    float2 ap0 = z, an0 = z, ap1 = z, an1 = z;
#pragma unroll 8
    for (int i = 0; i < DIM; ++i) {
      float2 w = *(const float2*)(sW + i * DIM + c0);
      float4 dd = *(const float4*)(&s_d[wave][i][0]);  // broadcast b128
      ap0.x = fmaf(dd.x, w.x, ap0.x);  ap0.y = fmaf(dd.x, w.y, ap0.y);
      an0.x = fmaf(dd.y, w.x, an0.x);  an0.y = fmaf(dd.y, w.y, an0.y);
      ap1.x = fmaf(dd.z, w.x, ap1.x);  ap1.y = fmaf(dd.z, w.y, ap1.y);
      an1.x = fmaf(dd.w, w.x, an1.x);  an1.y = fmaf(dd.w, w.y, an1.y);
    }

    float s0 = ap0.x * dp0.x + ap0.y * dp0.y - an0.x * dn0.x - an0.y * dn0.y;
    float s1 = ap1.x * dp1.x + ap1.y * dp1.y - an1.x * dn1.x - an1.y * dn1.y;
#pragma unroll
    for (int o = 32; o > 0; o >>= 1) {
      s0 += __shfl_xor(s0, o, 64);
      s1 += __shfl_xor(s1, o, 64);
    }
    if (lane == 0) {
      if (v0) partial[e0] = s0;
      if (v1) partial[e1] = s1;
    }
    __syncthreads();  // protect s_d before next pass overwrites
  }
}

// Single-block deterministic reduction: mean(relu(MARGIN + (pos - neg)))
__global__ __launch_bounds__(256) void reduce_kernel(const float* __restrict__ partial,
                                                     float* __restrict__ out) {
  float acc = 0.f;
  for (int i = threadIdx.x; i < BATCH; i += 256) {
    float v = MARGIN + partial[i];
    acc += (v > 0.f) ? v : 0.f;
  }
#pragma unroll
  for (int o = 32; o > 0; o >>= 1) acc += __shfl_xor(acc, o, 64);
  __shared__ float s[4];
  const int lane = threadIdx.x & 63, wave = threadIdx.x >> 6;
  if (lane == 0) s[wave] = acc;
  __syncthreads();
  if (threadIdx.x == 0) out[0] = (s[0] + s[1] + s[2] + s[3]) * (1.0f / BATCH);
}

extern "C" void kernel_launch(void* const* d_in, const int* in_sizes, int n_in,
                              void* d_out, int out_size, void* d_ws, size_t ws_size,
                              hipStream_t stream) {
  const float* pos_b = (const float*)d_in[0];
  const float* neg_b = (const float*)d_in[1];
  const int* r_idx = (const int*)d_in[2];
  const float* rel_emb = (const float*)d_in[3];
  float* out = (float*)d_out;

  int* ws_i = (int*)d_ws;
  float* partial = (float*)d_ws + WS_PARTIAL;
  int* cnt = ws_i + WS_CNT;
  int* start = ws_i + WS_START;
  int* cursor = ws_i + WS_CURSOR;
  int* order = ws_i + WS_ORDER;

  zero_kernel<<<1, 256, 0, stream>>>(cnt);
  count_kernel<<<BATCH / 256, 256, 0, stream>>>(r_idx, cnt);
  scan_kernel<<<1, 256, 0, stream>>>(cnt, start, cursor);
  scatter_kernel<<<BATCH / 256, 256, 0, stream>>>(r_idx, cursor, order);
  score_kernel<<<NREL, 256, DIM * DIM * sizeof(float), stream>>>(
      pos_b, neg_b, rel_emb, cnt, start, order, partial);
  reduce_kernel<<<1, 256, 0, stream>>>(partial, out);
}

// Round 3
// 47.375 us; speedup vs baseline: 1.7877x; 1.4369x over previous
//
#include <hip/hip_runtime.h>

#define BATCH 8192
#define DIM 128
#define NREL 1000
#define MARGIN 1.0f

// Workspace layout (4 B units):
//   [0      .. 8191 ]  partial  (float, per-element pos-neg score)
//   [8192   .. 9215 ]  cnt      (int, NREL padded to 1024)
//   [9216   .. 10239]  pstart   (int, padded exclusive scan)
//   [10240  .. 11263]  cursor   (int)
//   [11264  .. 22527]  order    (int, padded capacity 11264)
#define WS_PARTIAL 0
#define WS_CNT     8192
#define WS_PSTART  9216
#define WS_CURSOR  10240
#define WS_ORDER   11264
#define ORDER_CAP  11264  // >= max padded total (8192 + 3*1000 = 11192)

__global__ __launch_bounds__(256) void init_kernel(int* __restrict__ cnt,
                                                   int* __restrict__ order) {
  int i = blockIdx.x * 256 + threadIdx.x;
  if (i < 1024) cnt[i] = 0;
  if (i < ORDER_CAP) order[i] = -1;
}

__global__ __launch_bounds__(256) void count_kernel(const int* __restrict__ r_idx,
                                                    int* __restrict__ cnt) {
  int i = blockIdx.x * 256 + threadIdx.x;
  if (i < BATCH) atomicAdd(&cnt[r_idx[i]], 1);
}

// Exclusive scan over padded counts: pstart[r] = sum_{q<r} ceil(cnt[q]/4)*4.
__global__ __launch_bounds__(256) void scan_kernel(const int* __restrict__ cnt,
                                                   int* __restrict__ pstart,
                                                   int* __restrict__ cursor) {
  int tid = threadIdx.x, lane = tid & 63, wave = tid >> 6;
  int base = tid * 4;
  int c[4], lsum = 0;
#pragma unroll
  for (int k = 0; k < 4; ++k) {
    int i = base + k;
    c[k] = (i < NREL) ? ((cnt[i] + 3) & ~3) : 0;  // padded to multiple of 4
    lsum += c[k];
  }
  int v = lsum;
#pragma unroll
  for (int o = 1; o < 64; o <<= 1) {
    int u = __shfl_up(v, o, 64);
    if (lane >= o) v += u;
  }
  __shared__ int wsum[4];
  if (lane == 63) wsum[wave] = v;
  __syncthreads();
  int woff = 0;
  for (int w = 0; w < wave; ++w) woff += wsum[w];
  int toff = woff + v - lsum;
#pragma unroll
  for (int k = 0; k < 4; ++k) {
    int i = base + k;
    if (i < NREL) {
      pstart[i] = toff;
      cursor[i] = toff;
    }
    toff += c[k];
  }
}

__global__ __launch_bounds__(256) void scatter_kernel(const int* __restrict__ r_idx,
                                                      int* __restrict__ cursor,
                                                      int* __restrict__ order) {
  int i = blockIdx.x * 256 + threadIdx.x;
  if (i < BATCH) {
    int p = atomicAdd(&cursor[r_idx[i]], 1);
    order[p] = i;
  }
}

__device__ inline float2 dvec(const float* __restrict__ b, int c0) {
  float2 h = *(const float2*)(b + c0);
  float2 r = *(const float2*)(b + DIM + c0);
  float2 t = *(const float2*)(b + 2 * DIM + c0);
  return make_float2(fabsf(h.x + r.x - t.x), fabsf(h.y + r.y - t.y));
}

// One wave per 4 same-relation elements. W streamed from global (L2-hot:
// consecutive waves share the relation). Each 8 B W load feeds 16 FMAs.
// d-vectors in wave-private LDS, b128 broadcast reads, no __syncthreads.
__global__ __launch_bounds__(256) void score_kernel(
    const float* __restrict__ pos_b, const float* __restrict__ neg_b,
    const int* __restrict__ r_idx, const float* __restrict__ rel_emb,
    const int* __restrict__ order, float* __restrict__ partial) {
  __shared__ float s_d[4][DIM][8];  // [wave][row][{p0..p3,n0..n3}] = 16 KB
  const int tid = threadIdx.x, lane = tid & 63, wave = tid >> 6;
  const int g4 = (blockIdx.x * 4 + wave) * 4;
  int4 es = *(const int4*)(order + g4);
  if (es.x < 0) return;  // wave-uniform
  const int c0 = lane * 2;
  const int r = r_idx[es.x];
  const bool v1 = es.y >= 0, v2 = es.z >= 0, v3 = es.w >= 0;
  const int e1 = v1 ? es.y : es.x, e2 = v2 ? es.z : es.x, e3 = v3 ? es.w : es.x;

  const float2 z = make_float2(0.f, 0.f);
  float2 dp0 = dvec(pos_b + (size_t)es.x * 3 * DIM, c0);
  float2 dn0 = dvec(neg_b + (size_t)es.x * 3 * DIM, c0);
  float2 dp1 = v1 ? dvec(pos_b + (size_t)e1 * 3 * DIM, c0) : z;
  float2 dn1 = v1 ? dvec(neg_b + (size_t)e1 * 3 * DIM, c0) : z;
  float2 dp2 = v2 ? dvec(pos_b + (size_t)e2 * 3 * DIM, c0) : z;
  float2 dn2 = v2 ? dvec(neg_b + (size_t)e2 * 3 * DIM, c0) : z;
  float2 dp3 = v3 ? dvec(pos_b + (size_t)e3 * 3 * DIM, c0) : z;
  float2 dn3 = v3 ? dvec(neg_b + (size_t)e3 * 3 * DIM, c0) : z;

  *(float4*)&s_d[wave][c0][0]     = make_float4(dp0.x, dp1.x, dp2.x, dp3.x);
  *(float4*)&s_d[wave][c0][4]     = make_float4(dn0.x, dn1.x, dn2.x, dn3.x);
  *(float4*)&s_d[wave][c0 + 1][0] = make_float4(dp0.y, dp1.y, dp2.y, dp3.y);
  *(float4*)&s_d[wave][c0 + 1][4] = make_float4(dn0.y, dn1.y, dn2.y, dn3.y);
  // wave-private LDS: no barrier needed, in-wave lgkmcnt ordering suffices

  const float* W = rel_emb + (size_t)r * (DIM * DIM) + c0;
  float2 ap0 = z, ap1 = z, ap2 = z, ap3 = z;
  float2 an0 = z, an1 = z, an2 = z, an3 = z;
#pragma unroll 8
  for (int i = 0; i < DIM; ++i) {
    float2 wv = *(const float2*)(W + (size_t)i * DIM);
    float4 ddp = *(const float4*)&s_d[wave][i][0];  // broadcast
    float4 ddn = *(const float4*)&s_d[wave][i][4];  // broadcast
    ap0.x = fmaf(ddp.x, wv.x, ap0.x);  ap0.y = fmaf(ddp.x, wv.y, ap0.y);
    ap1.x = fmaf(ddp.y, wv.x, ap1.x);  ap1.y = fmaf(ddp.y, wv.y, ap1.y);
    ap2.x = fmaf(ddp.z, wv.x, ap2.x);  ap2.y = fmaf(ddp.z, wv.y, ap2.y);
    ap3.x = fmaf(ddp.w, wv.x, ap3.x);  ap3.y = fmaf(ddp.w, wv.y, ap3.y);
    an0.x = fmaf(ddn.x, wv.x, an0.x);  an0.y = fmaf(ddn.x, wv.y, an0.y);
    an1.x = fmaf(ddn.y, wv.x, an1.x);  an1.y = fmaf(ddn.y, wv.y, an1.y);
    an2.x = fmaf(ddn.z, wv.x, an2.x);  an2.y = fmaf(ddn.z, wv.y, an2.y);
    an3.x = fmaf(ddn.w, wv.x, an3.x);  an3.y = fmaf(ddn.w, wv.y, an3.y);
  }

  float s0 = ap0.x * dp0.x + ap0.y * dp0.y - an0.x * dn0.x - an0.y * dn0.y;
  float s1 = ap1.x * dp1.x + ap1.y * dp1.y - an1.x * dn1.x - an1.y * dn1.y;
  float s2 = ap2.x * dp2.x + ap2.y * dp2.y - an2.x * dn2.x - an2.y * dn2.y;
  float s3 = ap3.x * dp3.x + ap3.y * dp3.y - an3.x * dn3.x - an3.y * dn3.y;
#pragma unroll
  for (int o = 32; o > 0; o >>= 1) {
    s0 += __shfl_xor(s0, o, 64);
    s1 += __shfl_xor(s1, o, 64);
    s2 += __shfl_xor(s2, o, 64);
    s3 += __shfl_xor(s3, o, 64);
  }
  if (lane == 0) {
    partial[es.x] = s0;
    if (v1) partial[es.y] = s1;
    if (v2) partial[es.z] = s2;
    if (v3) partial[es.w] = s3;
  }
}

__global__ __launch_bounds__(256) void reduce_kernel(const float* __restrict__ partial,
                                                     float* __restrict__ out) {
  float acc = 0.f;
  for (int i = threadIdx.x; i < BATCH; i += 256) {
    float v = MARGIN + partial[i];
    acc += (v > 0.f) ? v : 0.f;
  }
#pragma unroll
  for (int o = 32; o > 0; o >>= 1) acc += __shfl_xor(acc, o, 64);
  __shared__ float s[4];
  const int lane = threadIdx.x & 63, wave = threadIdx.x >> 6;
  if (lane == 0) s[wave] = acc;
  __syncthreads();
  if (threadIdx.x == 0) out[0] = (s[0] + s[1] + s[2] + s[3]) * (1.0f / BATCH);
}

extern "C" void kernel_launch(void* const* d_in, const int* in_sizes, int n_in,
                              void* d_out, int out_size, void* d_ws, size_t ws_size,
                              hipStream_t stream) {
  const float* pos_b = (const float*)d_in[0];
  const float* neg_b = (const float*)d_in[1];
  const int* r_idx = (const int*)d_in[2];
  const float* rel_emb = (const float*)d_in[3];
  float* out = (float*)d_out;

  int* ws_i = (int*)d_ws;
  float* partial = (float*)d_ws + WS_PARTIAL;
  int* cnt = ws_i + WS_CNT;
  int* pstart = ws_i + WS_PSTART;
  int* cursor = ws_i + WS_CURSOR;
  int* order = ws_i + WS_ORDER;

  init_kernel<<<(ORDER_CAP + 255) / 256, 256, 0, stream>>>(cnt, order);
  count_kernel<<<BATCH / 256, 256, 0, stream>>>(r_idx, cnt);
  scan_kernel<<<1, 256, 0, stream>>>(cnt, pstart, cursor);
  scatter_kernel<<<BATCH / 256, 256, 0, stream>>>(r_idx, cursor, order);
  // 700 blocks * 4 waves * 4 elems = 11200 slots >= max padded total 11192
  score_kernel<<<700, 256, 0, stream>>>(pos_b, neg_b, r_idx, rel_emb, order,
                                        partial);
  reduce_kernel<<<1, 256, 0, stream>>>(partial, out);
}

// Round 4
// 46.449 us; speedup vs baseline: 1.8233x; 1.0199x over previous
//
#include <hip/hip_runtime.h>

#define BATCH 8192
#define DIM 128
#define NREL 1000
#define MARGIN 1.0f

// ws layout (4 B units): pA[8192] | pB[8192] | order[11264]
#define WS_PA 0
#define WS_PB 8192
#define WS_ORDER 16384
#define ORDER_CAP 11264  // >= 2800 groups * 4; max padded total = 8192+3*1000 = 11192

// Fused single-block counting sort: zero + count + pad-scan + init + scatter.
// 1024 threads, all counters/cursors in LDS.
__global__ __launch_bounds__(1024) void sort_kernel(const int* __restrict__ r_idx,
                                                    int* __restrict__ order) {
  __shared__ int s_cnt[1024];
  __shared__ int s_cur[1024];
  __shared__ int s_wsum[16];
  const int tid = threadIdx.x, lane = tid & 63, wave = tid >> 6;
  s_cnt[tid] = 0;
  __syncthreads();
  int my[8];
#pragma unroll
  for (int k = 0; k < 8; ++k) {
    my[k] = r_idx[tid + k * 1024];
    atomicAdd(&s_cnt[my[k]], 1);
  }
  __syncthreads();
  // exclusive scan of counts padded to multiples of 4
  const int c = (s_cnt[tid] + 3) & ~3;
  int v = c;
#pragma unroll
  for (int o = 1; o < 64; o <<= 1) {
    int u = __shfl_up(v, o, 64);
    if (lane >= o) v += u;
  }
  if (lane == 63) s_wsum[wave] = v;
  __syncthreads();
  int woff = 0;
  for (int w = 0; w < wave; ++w) woff += s_wsum[w];
  s_cur[tid] = woff + v - c;  // exclusive padded start = cursor
  for (int i = tid; i < ORDER_CAP; i += 1024) order[i] = -1;
  __syncthreads();  // cursors ready AND -1 init globally visible block-wide
#pragma unroll
  for (int k = 0; k < 8; ++k) {
    int p = atomicAdd(&s_cur[my[k]], 1);
    order[p] = tid + k * 1024;
  }
}

__device__ inline float2 dvec(const float* __restrict__ b, int c0) {
  float2 h = *(const float2*)(b + c0);
  float2 r = *(const float2*)(b + DIM + c0);
  float2 t = *(const float2*)(b + 2 * DIM + c0);
  return make_float2(fabsf(h.x + r.x - t.x), fabsf(h.y + r.y - t.y));
}

// 2 waves per 4-element same-relation group; wave half h covers rows
// h*64..h*64+63 (quadratic form is linear in row blocks: s = sA + sB).
// float4 W loads: lanes 0-31 row r, lanes 32-63 row r+1 -> contiguous 1 KB.
__global__ __launch_bounds__(256) void score_kernel(
    const float* __restrict__ pos_b, const float* __restrict__ neg_b,
    const int* __restrict__ r_idx, const float* __restrict__ rel_emb,
    const int* __restrict__ order, float* __restrict__ pA,
    float* __restrict__ pB) {
  __shared__ float s_d[4][DIM][8];  // wave-private: [row][{p0..p3,n0..n3}]
  const int tid = threadIdx.x, lane = tid & 63, wave = tid >> 6;
  const int pair = wave >> 1, half = wave & 1;
  const int g = blockIdx.x * 2 + pair;
  int4 es = *(const int4*)(order + g * 4);
  if (es.x < 0) return;  // wave-uniform
  const int c0 = lane * 2;
  const int r = r_idx[es.x];
  const bool v1 = es.y >= 0, v2 = es.z >= 0, v3 = es.w >= 0;
  const int e1 = v1 ? es.y : es.x, e2 = v2 ? es.z : es.x, e3 = v3 ? es.w : es.x;

  const float2 z = make_float2(0.f, 0.f);
  float2 dp0 = dvec(pos_b + (size_t)es.x * 3 * DIM, c0);
  float2 dn0 = dvec(neg_b + (size_t)es.x * 3 * DIM, c0);
  float2 dp1 = v1 ? dvec(pos_b + (size_t)e1 * 3 * DIM, c0) : z;
  float2 dn1 = v1 ? dvec(neg_b + (size_t)e1 * 3 * DIM, c0) : z;
  float2 dp2 = v2 ? dvec(pos_b + (size_t)e2 * 3 * DIM, c0) : z;
  float2 dn2 = v2 ? dvec(neg_b + (size_t)e2 * 3 * DIM, c0) : z;
  float2 dp3 = v3 ? dvec(pos_b + (size_t)e3 * 3 * DIM, c0) : z;
  float2 dn3 = v3 ? dvec(neg_b + (size_t)e3 * 3 * DIM, c0) : z;

  *(float4*)&s_d[wave][c0][0]     = make_float4(dp0.x, dp1.x, dp2.x, dp3.x);
  *(float4*)&s_d[wave][c0][4]     = make_float4(dn0.x, dn1.x, dn2.x, dn3.x);
  *(float4*)&s_d[wave][c0 + 1][0] = make_float4(dp0.y, dp1.y, dp2.y, dp3.y);
  *(float4*)&s_d[wave][c0 + 1][4] = make_float4(dn0.y, dn1.y, dn2.y, dn3.y);
  // wave-private LDS region: in-wave lgkmcnt ordering suffices, no barrier

  const int colb = (lane & 31) * 4;  // this lane's 4 columns
  const int rsel = lane >> 5;        // sub-row within each iter
  const int rowbase = half * 64;
  const float* W = rel_emb + (size_t)r * (DIM * DIM) +
                   (size_t)(rowbase + rsel) * DIM + colb;

  float4 fz = make_float4(0.f, 0.f, 0.f, 0.f);
  float4 ap0 = fz, ap1 = fz, ap2 = fz, ap3 = fz;
  float4 an0 = fz, an1 = fz, an2 = fz, an3 = fz;
#pragma unroll 4
  for (int it = 0; it < 32; ++it) {
    float4 wv = *(const float4*)(W + (size_t)(it * 2) * DIM);
    const int row = rowbase + it * 2 + rsel;
    float4 ddp = *(const float4*)&s_d[wave][row][0];  // 2-addr broadcast
    float4 ddn = *(const float4*)&s_d[wave][row][4];
    ap0.x = fmaf(ddp.x, wv.x, ap0.x); ap0.y = fmaf(ddp.x, wv.y, ap0.y);
    ap0.z = fmaf(ddp.x, wv.z, ap0.z); ap0.w = fmaf(ddp.x, wv.w, ap0.w);
    ap1.x = fmaf(ddp.y, wv.x, ap1.x); ap1.y = fmaf(ddp.y, wv.y, ap1.y);
    ap1.z = fmaf(ddp.y, wv.z, ap1.z); ap1.w = fmaf(ddp.y, wv.w, ap1.w);
    ap2.x = fmaf(ddp.z, wv.x, ap2.x); ap2.y = fmaf(ddp.z, wv.y, ap2.y);
    ap2.z = fmaf(ddp.z, wv.z, ap2.z); ap2.w = fmaf(ddp.z, wv.w, ap2.w);
    ap3.x = fmaf(ddp.w, wv.x, ap3.x); ap3.y = fmaf(ddp.w, wv.y, ap3.y);
    ap3.z = fmaf(ddp.w, wv.z, ap3.z); ap3.w = fmaf(ddp.w, wv.w, ap3.w);
    an0.x = fmaf(ddn.x, wv.x, an0.x); an0.y = fmaf(ddn.x, wv.y, an0.y);
    an0.z = fmaf(ddn.x, wv.z, an0.z); an0.w = fmaf(ddn.x, wv.w, an0.w);
    an1.x = fmaf(ddn.y, wv.x, an1.x); an1.y = fmaf(ddn.y, wv.y, an1.y);
    an1.z = fmaf(ddn.y, wv.z, an1.z); an1.w = fmaf(ddn.y, wv.w, an1.w);
    an2.x = fmaf(ddn.z, wv.x, an2.x); an2.y = fmaf(ddn.z, wv.y, an2.y);
    an2.z = fmaf(ddn.z, wv.z, an2.z); an2.w = fmaf(ddn.z, wv.w, an2.w);
    an3.x = fmaf(ddn.w, wv.x, an3.x); an3.y = fmaf(ddn.w, wv.y, an3.y);
    an3.z = fmaf(ddn.w, wv.z, an3.z); an3.w = fmaf(ddn.w, wv.w, an3.w);
  }

  // s_e = sum_k acc_e[col colb+k] * d_e[colb+k]; lanes l and l+32 hold
  // row-partial colaccs for the same columns -> the 64-lane reduce sums them.
  float s0 = 0.f, s1 = 0.f, s2 = 0.f, s3 = 0.f;
#define EPI(K, COMP)                                          \
  {                                                           \
    float4 dp4 = *(const float4*)&s_d[wave][colb + K][0];     \
    float4 dn4 = *(const float4*)&s_d[wave][colb + K][4];     \
    s0 += ap0.COMP * dp4.x - an0.COMP * dn4.x;                \
    s1 += ap1.COMP * dp4.y - an1.COMP * dn4.y;                \
    s2 += ap2.COMP * dp4.z - an2.COMP * dn4.z;                \
    s3 += ap3.COMP * dp4.w - an3.COMP * dn4.w;                \
  }
  EPI(0, x) EPI(1, y) EPI(2, z) EPI(3, w)
#undef EPI

#pragma unroll
  for (int o = 32; o > 0; o >>= 1) {
    s0 += __shfl_xor(s0, o, 64);
    s1 += __shfl_xor(s1, o, 64);
    s2 += __shfl_xor(s2, o, 64);
    s3 += __shfl_xor(s3, o, 64);
  }
  float* P = half ? pB : pA;
  if (lane == 0) {
    P[es.x] = s0;
    if (v1) P[es.y] = s1;
    if (v2) P[es.z] = s2;
    if (v3) P[es.w] = s3;
  }
}

__global__ __launch_bounds__(256) void reduce_kernel(const float* __restrict__ pA,
                                                     const float* __restrict__ pB,
                                                     float* __restrict__ out) {
  float acc = 0.f;
  for (int i = threadIdx.x; i < BATCH; i += 256) {
    float v = MARGIN + pA[i] + pB[i];
    acc += (v > 0.f) ? v : 0.f;
  }
#pragma unroll
  for (int o = 32; o > 0; o >>= 1) acc += __shfl_xor(acc, o, 64);
  __shared__ float s[4];
  const int lane = threadIdx.x & 63, wave = threadIdx.x >> 6;
  if (lane == 0) s[wave] = acc;
  __syncthreads();
  if (threadIdx.x == 0) out[0] = (s[0] + s[1] + s[2] + s[3]) * (1.0f / BATCH);
}

extern "C" void kernel_launch(void* const* d_in, const int* in_sizes, int n_in,
                              void* d_out, int out_size, void* d_ws, size_t ws_size,
                              hipStream_t stream) {
  const float* pos_b = (const float*)d_in[0];
  const float* neg_b = (const float*)d_in[1];
  const int* r_idx = (const int*)d_in[2];
  const float* rel_emb = (const float*)d_in[3];
  float* out = (float*)d_out;

  float* pA = (float*)d_ws + WS_PA;
  float* pB = (float*)d_ws + WS_PB;
  int* order = (int*)d_ws + WS_ORDER;

  sort_kernel<<<1, 1024, 0, stream>>>(r_idx, order);
  // 1400 blocks * 2 groups * 4 elems = 11200 slots >= padded total (<=11192)
  score_kernel<<<1400, 256, 0, stream>>>(pos_b, neg_b, r_idx, rel_emb, order,
                                         pA, pB);
  reduce_kernel<<<1, 256, 0, stream>>>(pA, pB, out);
}